// Round 10
// baseline (116.336 us; speedup 1.0000x reference)
//
#include <hip/hip_runtime.h>
#include <math.h>

// Problem constants
#define MM 4
#define BB 256
#define KK 64
#define HH 1024
#define NN 50
#define EE 1225
#define PP 64
#define CTOT 1375   // E + N*3
#define NPAD 1408   // cols padded to 22*64

// History: R6 revert = 123.8. R7 k2 2-deep prefetch = 120.1. R8 k2 32x64/704
// blocks = 117.8. R9 k4 1024 threads = 114.5. Mechanism confirmed 4x: these
// are latency-exposed micro-kernels; overlap capacity (ILP/TLP) pays.
// R10: same mechanism on kA — split per-graph GEMM into 2 blocks/graph
// (512 cols each, float2 W1 loads): halves the serial k-chain work per
// thread and raises grid to 868 (~3.4 blocks/CU).

typedef short short8 __attribute__((ext_vector_type(8)));
typedef float floatx4 __attribute__((ext_vector_type(4)));
typedef unsigned short ushort;

__device__ __forceinline__ ushort f2bf(float f) {
    union { float f; unsigned u; } v; v.f = f;
    unsigned r = v.u + 0x7fffu + ((v.u >> 16) & 1u);
    return (ushort)(r >> 16);
}

__device__ __forceinline__ float logsigm(float l) {
    // log sigmoid(-l) = -(max(l,0) + log1p(exp(-|l|)))
    return -(fmaxf(l, 0.0f) + log1pf(expf(-fabsf(l))));
}

__device__ __forceinline__ float wsum64(float v) {
    #pragma unroll
    for (int m = 1; m < 64; m <<= 1) v += __shfl_xor(v, m);
    return v;
}
__device__ __forceinline__ float wmax64(float v) {
    #pragma unroll
    for (int m = 1; m < 64; m <<= 1) v = fmaxf(v, __shfl_xor(v, m));
    return v;
}

// kA: per-graph work (blocks 0..511, TWO blocks per graph: half=id&1 covers
// 512 H-cols) + weight transpose (blocks 512..863) + perm-inverse table
// (blocks 864..867). KLD + edge extraction live in half==0 blocks only;
// z-compute (64 threads) duplicated in both halves (cheap).
// NOTE (prior session): keep a plain 3-kernel chain. Cooperative grid-sync
// fusion cost +78 us; atomic producer-consumer +46 us.
__global__ __launch_bounds__(256) void kA(const float* __restrict__ mean,
                                          const float* __restrict__ logvar,
                                          const float* __restrict__ eps,
                                          const float* __restrict__ W1,
                                          const float* __restrict__ b1,
                                          const float* __restrict__ WA,
                                          const float* __restrict__ WF,
                                          const float* __restrict__ A,
                                          const int*   __restrict__ perms,
                                          ushort* __restrict__ hB,
                                          ushort* __restrict__ Wt,
                                          int*   __restrict__ edgesG,
                                          int*   __restrict__ cntG,
                                          float* __restrict__ kldG,
                                          int*   __restrict__ ipG) {
    const int t = threadIdx.x;
    __shared__ float smem[64 * 65];
    __shared__ int cnt;

    if (blockIdx.x < 512) {
        // ---- per-graph half-block: b = id>>1, half = id&1 ----
        const int b = blockIdx.x >> 1;
        const int half = blockIdx.x & 1;
        float4* z4 = (float4*)smem;
        if (t == 0) cnt = 0;
        if (t < 64) {
            float mv = mean[b * 64 + t];
            float lv = logvar[b * 64 + t];
            float sd = expf(0.5f * lv);
            float4 z;
            z.x = mv + sd * eps[(0 * BB + b) * 64 + t];
            z.y = mv + sd * eps[(1 * BB + b) * 64 + t];
            z.z = mv + sd * eps[(2 * BB + b) * 64 + t];
            z.w = mv + sd * eps[(3 * BB + b) * 64 + t];
            z4[t] = z;
            if (half == 0) {
                // KLD (wave 0, one lane per latent dim)
                float term = 0.5f * (expf(lv) + mv * mv - 1.0f - lv);
                term = wsum64(term);
                if (t == 0) kldG[b] = term;
            }
        }
        __syncthreads();
        const int j0 = half * 512 + t * 2;
        float acc[4][2] = {};   // [m][jc]
        #pragma unroll 8
        for (int k = 0; k < 64; k++) {
            float2 w = *(const float2*)&W1[k * HH + j0];
            float4 z = z4[k];
            acc[0][0] += z.x * w.x; acc[0][1] += z.x * w.y;
            acc[1][0] += z.y * w.x; acc[1][1] += z.y * w.y;
            acc[2][0] += z.z * w.x; acc[2][1] += z.z * w.y;
            acc[3][0] += z.w * w.x; acc[3][1] += z.w * w.y;
        }
        float2 bb = *(const float2*)&b1[j0];
        #pragma unroll
        for (int m = 0; m < 4; m++) {
            unsigned u0 = ((unsigned)f2bf(fmaxf(acc[m][0] + bb.x, 0.f))) |
                          ((unsigned)f2bf(fmaxf(acc[m][1] + bb.y, 0.f)) << 16);
            *(unsigned*)&hB[(b * 4 + m) * HH + j0] = u0;
        }
        if (half == 0) {
            // ---- edge extraction: coalesced scan of A[b], lower triangle ----
            for (int x = t; x < 2500; x += 256) {
                int i = x / NN, j = x - i * NN;
                if (j < i) {
                    float a = A[b * 2500 + x];
                    if (a != 0.0f) { int id = atomicAdd(&cnt, 1); edgesG[b * 256 + id] = (i << 8) | j; }
                }
            }
            __syncthreads();
            if (t == 0) cntG[b] = cnt;
        }
    } else if (blockIdx.x < 864) {
        // ---- Wt[n][k] = transpose of [WA | WF] (bf16, zero-padded cols) ----
        const int id = blockIdx.x - 512;
        const int kt = id & 15, nt = id >> 4;
        float* T = smem;   // [64][65]
        const int k0 = kt * 64, n0 = nt * 64;
        #pragma unroll
        for (int i = 0; i < 16; i++) {
            int x = i * 256 + t;
            int kk = x >> 6, nn = x & 63;
            int gn = n0 + nn, gk = k0 + kk;
            float v = 0.f;
            if (gn < EE)        v = WA[gk * EE + gn];
            else if (gn < CTOT) v = WF[gk * 150 + (gn - EE)];
            T[kk * 65 + nn] = v;
        }
        __syncthreads();
        #pragma unroll
        for (int i = 0; i < 16; i++) {
            int x = i * 256 + t;
            int nn = x >> 6, kk = x & 63;
            Wt[(n0 + nn) * 1024 + k0 + kk] = f2bf(T[kk * 65 + nn]);
        }
    } else {
        // ---- ipG[p][node] = position of node in perm p (stride 51, b-independent) ----
        const int id = blockIdx.x - 864;   // 0..3, 16 perms each
        for (int x = id * 800 + t; x < (id + 1) * 800; x += 256) {
            int p = x / NN, i = x - p * NN;
            ipG[p * 51 + perms[x]] = i;
        }
    }
}

// K2: MFMA GEMM logits[1024][1375] = hB @ Wt^T with fused epilogue.
// R8 structure (kept): 32x64 tile, grid 22x32 = 704 blocks (~2.75 blocks/CU),
// 4 waves (2x2), 2-deep register prefetch (R/S sets). LDS 27.6KB.
__global__ __launch_bounds__(256) void k2(const ushort* __restrict__ hB,
                                          const ushort* __restrict__ Wt,
                                          const float* __restrict__ bA,
                                          const float* __restrict__ bF,
                                          float* __restrict__ Lbar,
                                          float* __restrict__ SnegP,
                                          float* __restrict__ lgF) {
    const int ct = blockIdx.x;   // 0..21
    const int rt = blockIdx.y;   // 0..31
    const int t = threadIdx.x;
    const int w = t >> 6, lane = t & 63;
    const int wm = w >> 1, wn = w & 1;
    const int quad = lane >> 4, l16 = lane & 15;
    __shared__ short As[2][32][72];
    __shared__ short Bs[2][64][72];
    floatx4 acc[2] = {};
    const int row0 = rt * 32, col0 = ct * 64;

    const int r0 = t >> 3, koA = (t & 7) * 8;
    const ushort* pA0 = hB + (row0 + r0) * 1024 + koA;   // 32 rows x 8 loaders
    const ushort* pB0 = Wt + (col0 + r0) * 1024 + koA;
    const ushort* pB1 = pB0 + 32 * 1024;

    short8 ra0, rb0, rb1;   // set R: chunk ch+1 in flight
    short8 sa0, sb0, sb1;   // set S: chunk ch+2 in flight

#define MFMA_FROM(B) { \
        _Pragma("unroll") \
        for (int kk = 0; kk < 2; kk++) { \
            int ko = kk * 32 + quad * 8; \
            short8 a0 = *(const short8*)&As[B][wm * 16 + l16][ko]; \
            short8 b0 = *(const short8*)&Bs[B][wn * 32 + l16][ko]; \
            short8 b1 = *(const short8*)&Bs[B][wn * 32 + 16 + l16][ko]; \
            acc[0] = __builtin_amdgcn_mfma_f32_16x16x32_bf16(a0, b0, acc[0], 0, 0, 0); \
            acc[1] = __builtin_amdgcn_mfma_f32_16x16x32_bf16(a0, b1, acc[1], 0, 0, 0); \
        } }

    // Prologue: chunk 0 -> buf0; issue chunk 1 into R.
    ra0 = *(const short8*)(pA0);
    rb0 = *(const short8*)(pB0);
    rb1 = *(const short8*)(pB1);
    *(short8*)&As[0][r0][koA] = ra0;
    *(short8*)&Bs[0][r0][koA] = rb0;
    *(short8*)&Bs[0][r0 + 32][koA] = rb1;
    ra0 = *(const short8*)(pA0 + 64);
    rb0 = *(const short8*)(pB0 + 64);
    rb1 = *(const short8*)(pB1 + 64);
    __syncthreads();

    #pragma unroll
    for (int ch = 0; ch < 16; ch += 2) {
        // EVEN chunk ch: compute buf0; R holds ch+1; issue S <- ch+2.
        if (ch + 2 < 16) {
            const int off = (ch + 2) * 64;
            sa0 = *(const short8*)(pA0 + off);
            sb0 = *(const short8*)(pB0 + off);
            sb1 = *(const short8*)(pB1 + off);
        }
        MFMA_FROM(0)
        *(short8*)&As[1][r0][koA] = ra0;   // ch+1 -> buf1 (issued 1 iter ago)
        *(short8*)&Bs[1][r0][koA] = rb0;
        *(short8*)&Bs[1][r0 + 32][koA] = rb1;
        __syncthreads();
        // ODD chunk ch+1: compute buf1; S holds ch+2; issue R <- ch+3.
        if (ch + 3 < 16) {
            const int off = (ch + 3) * 64;
            ra0 = *(const short8*)(pA0 + off);
            rb0 = *(const short8*)(pB0 + off);
            rb1 = *(const short8*)(pB1 + off);
        }
        MFMA_FROM(1)
        if (ch + 2 < 16) {
            *(short8*)&As[0][r0][koA] = sa0;   // ch+2 -> buf0
            *(short8*)&Bs[0][r0][koA] = sb0;
            *(short8*)&Bs[0][r0 + 32][koA] = sb1;
            __syncthreads();
        }
    }
#undef MFMA_FROM

    // Epilogue: C/D layout col=lane&15, row=quad*4+reg -> lane's 4 regs = graph b, m=0..3
    {
        const int grow = row0 + wm * 16 + quad * 4;
        const int b = grow >> 2;
        float sn0 = 0.f, sn1 = 0.f, sn2 = 0.f, sn3 = 0.f;
        #pragma unroll
        for (int ni = 0; ni < 2; ni++) {
            int gc = col0 + wn * 32 + ni * 16 + l16;
            floatx4 a = acc[ni];
            if (gc < EE) {
                float bias = bA[gc];
                float l0 = a[0] + bias, l1 = a[1] + bias, l2 = a[2] + bias, l3 = a[3] + bias;
                Lbar[b * EE + gc] = 0.25f * (l0 + l1 + l2 + l3);
                sn0 += logsigm(l0); sn1 += logsigm(l1); sn2 += logsigm(l2); sn3 += logsigm(l3);
            } else if (gc < CTOT) {
                int c2 = gc - EE;
                float bias = bF[c2];
                lgF[(b * 4 + 0) * 150 + c2] = a[0] + bias;
                lgF[(b * 4 + 1) * 150 + c2] = a[1] + bias;
                lgF[(b * 4 + 2) * 150 + c2] = a[2] + bias;
                lgF[(b * 4 + 3) * 150 + c2] = a[3] + bias;
            }
        }
        #pragma unroll
        for (int msk = 1; msk < 16; msk <<= 1) {
            sn0 += __shfl_xor(sn0, msk);
            sn1 += __shfl_xor(sn1, msk);
            sn2 += __shfl_xor(sn2, msk);
            sn3 += __shfl_xor(sn3, msk);
        }
        if (l16 == 0) {
            const int o = ct * 2 + wn;
            SnegP[(b * 4 + 0) * 44 + o] = sn0;
            SnegP[(b * 4 + 1) * 44 + o] = sn1;
            SnegP[(b * 4 + 2) * 44 + o] = sn2;
            SnegP[(b * 4 + 3) * 44 + o] = sn3;
        }
    }
}

// K4: per-graph finalization. grid 256, 1024 threads (16 waves = 4 waves/SIMD).
// lane = permutation (64 lanes = 64 perms), wave = edge-stripe (16-way).
__global__ __launch_bounds__(1024) void k4(const float* __restrict__ Fx,
                                           const float* __restrict__ coeff,
                                           const int* __restrict__ ipG,
                                           const float* __restrict__ Lbar,
                                           const float* __restrict__ SnegP,
                                           const float* __restrict__ lgF,
                                           const int* __restrict__ edgesG,
                                           const int* __restrict__ cntG,
                                           const float* __restrict__ kldG,
                                           float* __restrict__ out) {
    const int b = blockIdx.x;
    const int t = threadIdx.x;
    const int w = t >> 6, lane = t & 63;
    __shared__ int   ip[PP * 51];      // [perm][node], stride 51 (odd -> 2-way banks)
    __shared__ float LbF[NN * 51];     // full symmetric matrix
    __shared__ int   edges[256];
    __shared__ float lgfs[600];
    __shared__ float mred[4], snegR[4];
    __shared__ float psum[16][64];

    const int ne = cntG[b];
    for (int x = t; x < PP * 51; x += 1024) ip[x] = ipG[x];
    for (int x = t; x < 2500; x += 1024) {
        int i = x / NN, j = x - i * NN;
        if (j < i) {
            float v = Lbar[b * EE + i * (i - 1) / 2 + j];
            LbF[i * 51 + j] = v;
            LbF[j * 51 + i] = v;
        }
    }
    if (t < 600) lgfs[t] = lgF[b * 600 + t];
    if (t < ne) edges[t] = edgesG[b * 256 + t];
    __syncthreads();

    // perm partial sums: all 64 perms in flight per wave, edges striped by wave
    {
        const int ipB = lane * 51;
        float acc = 0.f;
        for (int x = w; x < ne; x += 16) {
            int ed = edges[x];
            int iu = ip[ipB + (ed >> 8)];
            int iv = ip[ipB + (ed & 255)];
            acc += LbF[iu * 51 + iv];
        }
        psum[w][lane] = acc;
    }

    // Fx terms + Sneg partial reduce: waves 0..3 handle sample m = w
    if (w < 4) {
        float l0 = 0.f, l1 = 0.f, l2 = -INFINITY, x0 = 0.f, x1 = 0.f, x2 = 0.f;
        bool v = lane < NN;
        if (v) {
            l0 = lgfs[w * 150 + lane * 3 + 0];
            l1 = lgfs[w * 150 + lane * 3 + 1];
            l2 = lgfs[w * 150 + lane * 3 + 2];
            x0 = Fx[b * 150 + lane * 3 + 0];
            x1 = Fx[b * 150 + lane * 3 + 1];
            x2 = Fx[b * 150 + lane * 3 + 2];
        }
        float mx = wmax64(l2);
        float es = v ? expf(l2 - mx) : 0.f;
        es = wsum64(es);
        float lse = mx + logf(es);
        float val = 0.f;
        if (v) {
            val = coeff[0] * (logsigm(l0) + x0 * l0)
                + coeff[1] * (logsigm(l1) + x1 * l1)
                + coeff[2] * (x2 * (l2 - lse));
        }
        val = wsum64(val);
        float sv = (lane < 44) ? SnegP[(b * 4 + w) * 44 + lane] : 0.f;
        sv = wsum64(sv);
        if (lane == 0) { mred[w] = val; snegR[w] = sv; }
    }
    __syncthreads();

    if (w == 0) {
        float s = psum[0][lane];
        #pragma unroll
        for (int i = 1; i < 16; i++) s += psum[i][lane];
        float dmax = wmax64(s);
        if (lane == 0) {
            float sbar = 0.25f * (snegR[0] + snegR[1] + snegR[2] + snegR[3]);
            float fxv  = 0.25f * (mred[0] + mred[1] + mred[2] + mred[3]);
            out[b] = (sbar + dmax) + fxv - kldG[b];
        }
    }
}

extern "C" void kernel_launch(void* const* d_in, const int* in_sizes, int n_in,
                              void* d_out, int out_size, void* d_ws, size_t ws_size,
                              hipStream_t stream) {
    const float* mean   = (const float*)d_in[0];
    const float* logvar = (const float*)d_in[1];
    const float* eps    = (const float*)d_in[2];
    const float* W1     = (const float*)d_in[3];
    const float* b1     = (const float*)d_in[4];
    const float* WA     = (const float*)d_in[5];
    const float* bA     = (const float*)d_in[6];
    const float* WF     = (const float*)d_in[7];
    const float* bF     = (const float*)d_in[8];
    const float* A      = (const float*)d_in[9];
    const float* Fx     = (const float*)d_in[10];
    const float* coeff  = (const float*)d_in[11];
    const int*   perms  = (const int*)d_in[12];
    float* out = (float*)d_out;

    ushort* Wt   = (ushort*)d_ws;               // 1408*1024 bf16
    ushort* hB   = Wt + NPAD * 1024;            // 1024*1024 bf16
    float*  Lbar = (float*)(hB + 1024 * 1024);  // 256*1225
    float*  SnegP = Lbar + BB * EE;             // 256*4*44 partials (written by k2)
    float*  lgF  = SnegP + 256 * 4 * 44;        // 1024*150
    int*    edgesG = (int*)(lgF + 1024 * 150);  // 256*256
    int*    cntG   = edgesG + 256 * 256;        // 256
    float*  kldG   = (float*)(cntG + 256);      // 256
    int*    ipG    = (int*)(kldG + 256);        // 64*51

    kA<<<dim3(868), dim3(256), 0, stream>>>(mean, logvar, eps, W1, b1, WA, WF, A, perms,
                                            hB, Wt, edgesG, cntG, kldG, ipG);
    k2<<<dim3(22, 32), dim3(256), 0, stream>>>(hB, Wt, bA, bF, Lbar, SnegP, lgF);
    k4<<<dim3(BB), dim3(1024), 0, stream>>>(Fx, coeff, ipG, Lbar, SnegP, lgF,
                                            edgesG, cntG, kldG, out);
}

// Round 12
// 112.196 us; speedup vs baseline: 1.0369x; 1.0369x over previous
//
#include <hip/hip_runtime.h>
#include <math.h>

// Problem constants
#define MM 4
#define BB 256
#define KK 64
#define HH 1024
#define NN 50
#define EE 1225
#define PP 64
#define CTOT 1375   // E + N*3
#define NPAD 1408   // cols padded to 22*64

// History: R6=123.8, R7 k2 prefetch=120.1, R8 k2 704 blocks=117.8, R9 k4
// 1024thr=114.5 (best). R10 kA 2-blocks/graph REGRESSED +1.9: it kept W1
// traffic constant (1 GB!). Byte-count insight: R9's kA streams ALL of W1
// (4MB fp32) through every block's L1 -> ~1 GB L2 traffic, kA ~ 10-14 us =
// the real dominant kernel. R11: tiled GEMM for hB = Z @ W1 (16x16 blocks of
// 64x64 tiles, W1 tile in LDS) -> W1 traffic 64 MB (16x less). Z subtile
// built in-LDS from mean/logvar/eps with identical per-element FP order.
// R12: identical resubmission — R11 bench was an infra failure (container
// died twice), not a kernel signal.

typedef short short8 __attribute__((ext_vector_type(8)));
typedef float floatx4 __attribute__((ext_vector_type(4)));
typedef unsigned short ushort;

__device__ __forceinline__ ushort f2bf(float f) {
    union { float f; unsigned u; } v; v.f = f;
    unsigned r = v.u + 0x7fffu + ((v.u >> 16) & 1u);
    return (ushort)(r >> 16);
}

__device__ __forceinline__ float logsigm(float l) {
    // log sigmoid(-l) = -(max(l,0) + log1p(exp(-|l|)))
    return -(fmaxf(l, 0.0f) + log1pf(expf(-fabsf(l))));
}

__device__ __forceinline__ float wsum64(float v) {
    #pragma unroll
    for (int m = 1; m < 64; m <<= 1) v += __shfl_xor(v, m);
    return v;
}
__device__ __forceinline__ float wmax64(float v) {
    #pragma unroll
    for (int m = 1; m < 64; m <<= 1) v = fmaxf(v, __shfl_xor(v, m));
    return v;
}

// kA block map (grid 868):
//   0..255   : hB GEMM tiles (rb = id>>4, cb = id&15), 64x64 output each
//   256..511 : per-graph edge extraction + KLD (b = id-256)
//   512..863 : Wt transpose
//   864..867 : ipG perm-inverse table
// NOTE (prior session): keep a plain 3-kernel chain. Cooperative grid-sync
// fusion cost +78 us; atomic producer-consumer +46 us.
__global__ __launch_bounds__(256) void kA(const float* __restrict__ mean,
                                          const float* __restrict__ logvar,
                                          const float* __restrict__ eps,
                                          const float* __restrict__ W1,
                                          const float* __restrict__ b1,
                                          const float* __restrict__ WA,
                                          const float* __restrict__ WF,
                                          const float* __restrict__ A,
                                          const int*   __restrict__ perms,
                                          ushort* __restrict__ hB,
                                          ushort* __restrict__ Wt,
                                          int*   __restrict__ edgesG,
                                          int*   __restrict__ cntG,
                                          float* __restrict__ kldG,
                                          int*   __restrict__ ipG) {
    const int t = threadIdx.x;
    __shared__ float smem[64 * 65 + 64 * 64];   // Zs[64][65] | Ws[64][64]
    __shared__ int cnt;

    if (blockIdx.x < 256) {
        // ---- hB GEMM tile: rows rb*64.. (graphs rb*16..rb*16+15), cols cb*64.. ----
        const int rb = blockIdx.x >> 4, cb = blockIdx.x & 15;
        float* Zs = smem;            // [64][65]
        float* Ws = smem + 64 * 65;  // [64][64]
        // Build Z subtile (identical per-element FP order to the original).
        for (int x = t; x < 4096; x += 256) {
            int row = x >> 6, k = x & 63;
            int b = rb * 16 + (row >> 2), m = row & 3;
            float mv = mean[b * 64 + k];
            float sd = expf(0.5f * logvar[b * 64 + k]);
            Zs[row * 65 + k] = mv + sd * eps[(m * BB + b) * 64 + k];
        }
        // Stage W1 tile [64 k][64 cols].
        for (int x = t; x < 1024; x += 256) {
            int k = x >> 4, c4 = (x & 15) * 4;
            *(float4*)&Ws[k * 64 + c4] = *(const float4*)&W1[k * HH + cb * 64 + c4];
        }
        __syncthreads();
        // Register-blocked 4x4: thread (tr = t>>4, tc = t&15).
        const int tr = t >> 4, tc = t & 15;
        float acc[4][4] = {};   // [ri][cj]
        #pragma unroll 8
        for (int k = 0; k < 64; k++) {
            float4 w = *(const float4*)&Ws[k * 64 + tc * 4];
            float z0 = Zs[(tr * 4 + 0) * 65 + k];
            float z1 = Zs[(tr * 4 + 1) * 65 + k];
            float z2 = Zs[(tr * 4 + 2) * 65 + k];
            float z3 = Zs[(tr * 4 + 3) * 65 + k];
            acc[0][0] += z0 * w.x; acc[0][1] += z0 * w.y; acc[0][2] += z0 * w.z; acc[0][3] += z0 * w.w;
            acc[1][0] += z1 * w.x; acc[1][1] += z1 * w.y; acc[1][2] += z1 * w.z; acc[1][3] += z1 * w.w;
            acc[2][0] += z2 * w.x; acc[2][1] += z2 * w.y; acc[2][2] += z2 * w.z; acc[2][3] += z2 * w.w;
            acc[3][0] += z3 * w.x; acc[3][1] += z3 * w.y; acc[3][2] += z3 * w.z; acc[3][3] += z3 * w.w;
        }
        const int j0 = cb * 64 + tc * 4;
        float4 bb = *(const float4*)&b1[j0];
        #pragma unroll
        for (int i = 0; i < 4; i++) {
            const int grow = rb * 64 + tr * 4 + i;
            unsigned u0 = ((unsigned)f2bf(fmaxf(acc[i][0] + bb.x, 0.f))) |
                          ((unsigned)f2bf(fmaxf(acc[i][1] + bb.y, 0.f)) << 16);
            unsigned u1 = ((unsigned)f2bf(fmaxf(acc[i][2] + bb.z, 0.f))) |
                          ((unsigned)f2bf(fmaxf(acc[i][3] + bb.w, 0.f)) << 16);
            uint2 u; u.x = u0; u.y = u1;
            *(uint2*)&hB[grow * HH + j0] = u;
        }
    } else if (blockIdx.x < 512) {
        // ---- per-graph edges + KLD ----
        const int b = blockIdx.x - 256;
        if (t == 0) cnt = 0;
        if (t < 64) {
            float mv = mean[b * 64 + t];
            float lv = logvar[b * 64 + t];
            float term = 0.5f * (expf(lv) + mv * mv - 1.0f - lv);
            term = wsum64(term);
            if (t == 0) kldG[b] = term;
        }
        __syncthreads();
        for (int x = t; x < 2500; x += 256) {
            int i = x / NN, j = x - i * NN;
            if (j < i) {
                float a = A[b * 2500 + x];
                if (a != 0.0f) { int id = atomicAdd(&cnt, 1); edgesG[b * 256 + id] = (i << 8) | j; }
            }
        }
        __syncthreads();
        if (t == 0) cntG[b] = cnt;
    } else if (blockIdx.x < 864) {
        // ---- Wt[n][k] = transpose of [WA | WF] (bf16, zero-padded cols) ----
        const int id = blockIdx.x - 512;
        const int kt = id & 15, nt = id >> 4;
        float* T = smem;   // [64][65]
        const int k0 = kt * 64, n0 = nt * 64;
        #pragma unroll
        for (int i = 0; i < 16; i++) {
            int x = i * 256 + t;
            int kk = x >> 6, nn = x & 63;
            int gn = n0 + nn, gk = k0 + kk;
            float v = 0.f;
            if (gn < EE)        v = WA[gk * EE + gn];
            else if (gn < CTOT) v = WF[gk * 150 + (gn - EE)];
            T[kk * 65 + nn] = v;
        }
        __syncthreads();
        #pragma unroll
        for (int i = 0; i < 16; i++) {
            int x = i * 256 + t;
            int nn = x >> 6, kk = x & 63;
            Wt[(n0 + nn) * 1024 + k0 + kk] = f2bf(T[kk * 65 + nn]);
        }
    } else {
        // ---- ipG[p][node] = position of node in perm p (stride 51, b-independent) ----
        const int id = blockIdx.x - 864;   // 0..3, 16 perms each
        for (int x = id * 800 + t; x < (id + 1) * 800; x += 256) {
            int p = x / NN, i = x - p * NN;
            ipG[p * 51 + perms[x]] = i;
        }
    }
}

// K2: MFMA GEMM logits[1024][1375] = hB @ Wt^T with fused epilogue.
// R8 structure (kept): 32x64 tile, grid 22x32 = 704 blocks (~2.75 blocks/CU),
// 4 waves (2x2), 2-deep register prefetch (R/S sets). LDS 27.6KB.
__global__ __launch_bounds__(256) void k2(const ushort* __restrict__ hB,
                                          const ushort* __restrict__ Wt,
                                          const float* __restrict__ bA,
                                          const float* __restrict__ bF,
                                          float* __restrict__ Lbar,
                                          float* __restrict__ SnegP,
                                          float* __restrict__ lgF) {
    const int ct = blockIdx.x;   // 0..21
    const int rt = blockIdx.y;   // 0..31
    const int t = threadIdx.x;
    const int w = t >> 6, lane = t & 63;
    const int wm = w >> 1, wn = w & 1;
    const int quad = lane >> 4, l16 = lane & 15;
    __shared__ short As[2][32][72];
    __shared__ short Bs[2][64][72];
    floatx4 acc[2] = {};
    const int row0 = rt * 32, col0 = ct * 64;

    const int r0 = t >> 3, koA = (t & 7) * 8;
    const ushort* pA0 = hB + (row0 + r0) * 1024 + koA;   // 32 rows x 8 loaders
    const ushort* pB0 = Wt + (col0 + r0) * 1024 + koA;
    const ushort* pB1 = pB0 + 32 * 1024;

    short8 ra0, rb0, rb1;   // set R: chunk ch+1 in flight
    short8 sa0, sb0, sb1;   // set S: chunk ch+2 in flight

#define MFMA_FROM(B) { \
        _Pragma("unroll") \
        for (int kk = 0; kk < 2; kk++) { \
            int ko = kk * 32 + quad * 8; \
            short8 a0 = *(const short8*)&As[B][wm * 16 + l16][ko]; \
            short8 b0 = *(const short8*)&Bs[B][wn * 32 + l16][ko]; \
            short8 b1 = *(const short8*)&Bs[B][wn * 32 + 16 + l16][ko]; \
            acc[0] = __builtin_amdgcn_mfma_f32_16x16x32_bf16(a0, b0, acc[0], 0, 0, 0); \
            acc[1] = __builtin_amdgcn_mfma_f32_16x16x32_bf16(a0, b1, acc[1], 0, 0, 0); \
        } }

    // Prologue: chunk 0 -> buf0; issue chunk 1 into R.
    ra0 = *(const short8*)(pA0);
    rb0 = *(const short8*)(pB0);
    rb1 = *(const short8*)(pB1);
    *(short8*)&As[0][r0][koA] = ra0;
    *(short8*)&Bs[0][r0][koA] = rb0;
    *(short8*)&Bs[0][r0 + 32][koA] = rb1;
    ra0 = *(const short8*)(pA0 + 64);
    rb0 = *(const short8*)(pB0 + 64);
    rb1 = *(const short8*)(pB1 + 64);
    __syncthreads();

    #pragma unroll
    for (int ch = 0; ch < 16; ch += 2) {
        // EVEN chunk ch: compute buf0; R holds ch+1; issue S <- ch+2.
        if (ch + 2 < 16) {
            const int off = (ch + 2) * 64;
            sa0 = *(const short8*)(pA0 + off);
            sb0 = *(const short8*)(pB0 + off);
            sb1 = *(const short8*)(pB1 + off);
        }
        MFMA_FROM(0)
        *(short8*)&As[1][r0][koA] = ra0;   // ch+1 -> buf1 (issued 1 iter ago)
        *(short8*)&Bs[1][r0][koA] = rb0;
        *(short8*)&Bs[1][r0 + 32][koA] = rb1;
        __syncthreads();
        // ODD chunk ch+1: compute buf1; S holds ch+2; issue R <- ch+3.
        if (ch + 3 < 16) {
            const int off = (ch + 3) * 64;
            ra0 = *(const short8*)(pA0 + off);
            rb0 = *(const short8*)(pB0 + off);
            rb1 = *(const short8*)(pB1 + off);
        }
        MFMA_FROM(1)
        if (ch + 2 < 16) {
            *(short8*)&As[0][r0][koA] = sa0;   // ch+2 -> buf0
            *(short8*)&Bs[0][r0][koA] = sb0;
            *(short8*)&Bs[0][r0 + 32][koA] = sb1;
            __syncthreads();
        }
    }
#undef MFMA_FROM

    // Epilogue: C/D layout col=lane&15, row=quad*4+reg -> lane's 4 regs = graph b, m=0..3
    {
        const int grow = row0 + wm * 16 + quad * 4;
        const int b = grow >> 2;
        float sn0 = 0.f, sn1 = 0.f, sn2 = 0.f, sn3 = 0.f;
        #pragma unroll
        for (int ni = 0; ni < 2; ni++) {
            int gc = col0 + wn * 32 + ni * 16 + l16;
            floatx4 a = acc[ni];
            if (gc < EE) {
                float bias = bA[gc];
                float l0 = a[0] + bias, l1 = a[1] + bias, l2 = a[2] + bias, l3 = a[3] + bias;
                Lbar[b * EE + gc] = 0.25f * (l0 + l1 + l2 + l3);
                sn0 += logsigm(l0); sn1 += logsigm(l1); sn2 += logsigm(l2); sn3 += logsigm(l3);
            } else if (gc < CTOT) {
                int c2 = gc - EE;
                float bias = bF[c2];
                lgF[(b * 4 + 0) * 150 + c2] = a[0] + bias;
                lgF[(b * 4 + 1) * 150 + c2] = a[1] + bias;
                lgF[(b * 4 + 2) * 150 + c2] = a[2] + bias;
                lgF[(b * 4 + 3) * 150 + c2] = a[3] + bias;
            }
        }
        #pragma unroll
        for (int msk = 1; msk < 16; msk <<= 1) {
            sn0 += __shfl_xor(sn0, msk);
            sn1 += __shfl_xor(sn1, msk);
            sn2 += __shfl_xor(sn2, msk);
            sn3 += __shfl_xor(sn3, msk);
        }
        if (l16 == 0) {
            const int o = ct * 2 + wn;
            SnegP[(b * 4 + 0) * 44 + o] = sn0;
            SnegP[(b * 4 + 1) * 44 + o] = sn1;
            SnegP[(b * 4 + 2) * 44 + o] = sn2;
            SnegP[(b * 4 + 3) * 44 + o] = sn3;
        }
    }
}

// K4: per-graph finalization. grid 256, 1024 threads (16 waves = 4 waves/SIMD).
// lane = permutation (64 lanes = 64 perms), wave = edge-stripe (16-way).
__global__ __launch_bounds__(1024) void k4(const float* __restrict__ Fx,
                                           const float* __restrict__ coeff,
                                           const int* __restrict__ ipG,
                                           const float* __restrict__ Lbar,
                                           const float* __restrict__ SnegP,
                                           const float* __restrict__ lgF,
                                           const int* __restrict__ edgesG,
                                           const int* __restrict__ cntG,
                                           const float* __restrict__ kldG,
                                           float* __restrict__ out) {
    const int b = blockIdx.x;
    const int t = threadIdx.x;
    const int w = t >> 6, lane = t & 63;
    __shared__ int   ip[PP * 51];      // [perm][node], stride 51 (odd -> 2-way banks)
    __shared__ float LbF[NN * 51];     // full symmetric matrix
    __shared__ int   edges[256];
    __shared__ float lgfs[600];
    __shared__ float mred[4], snegR[4];
    __shared__ float psum[16][64];

    const int ne = cntG[b];
    for (int x = t; x < PP * 51; x += 1024) ip[x] = ipG[x];
    for (int x = t; x < 2500; x += 1024) {
        int i = x / NN, j = x - i * NN;
        if (j < i) {
            float v = Lbar[b * EE + i * (i - 1) / 2 + j];
            LbF[i * 51 + j] = v;
            LbF[j * 51 + i] = v;
        }
    }
    if (t < 600) lgfs[t] = lgF[b * 600 + t];
    if (t < ne) edges[t] = edgesG[b * 256 + t];
    __syncthreads();

    // perm partial sums: all 64 perms in flight per wave, edges striped by wave
    {
        const int ipB = lane * 51;
        float acc = 0.f;
        for (int x = w; x < ne; x += 16) {
            int ed = edges[x];
            int iu = ip[ipB + (ed >> 8)];
            int iv = ip[ipB + (ed & 255)];
            acc += LbF[iu * 51 + iv];
        }
        psum[w][lane] = acc;
    }

    // Fx terms + Sneg partial reduce: waves 0..3 handle sample m = w
    if (w < 4) {
        float l0 = 0.f, l1 = 0.f, l2 = -INFINITY, x0 = 0.f, x1 = 0.f, x2 = 0.f;
        bool v = lane < NN;
        if (v) {
            l0 = lgfs[w * 150 + lane * 3 + 0];
            l1 = lgfs[w * 150 + lane * 3 + 1];
            l2 = lgfs[w * 150 + lane * 3 + 2];
            x0 = Fx[b * 150 + lane * 3 + 0];
            x1 = Fx[b * 150 + lane * 3 + 1];
            x2 = Fx[b * 150 + lane * 3 + 2];
        }
        float mx = wmax64(l2);
        float es = v ? expf(l2 - mx) : 0.f;
        es = wsum64(es);
        float lse = mx + logf(es);
        float val = 0.f;
        if (v) {
            val = coeff[0] * (logsigm(l0) + x0 * l0)
                + coeff[1] * (logsigm(l1) + x1 * l1)
                + coeff[2] * (x2 * (l2 - lse));
        }
        val = wsum64(val);
        float sv = (lane < 44) ? SnegP[(b * 4 + w) * 44 + lane] : 0.f;
        sv = wsum64(sv);
        if (lane == 0) { mred[w] = val; snegR[w] = sv; }
    }
    __syncthreads();

    if (w == 0) {
        float s = psum[0][lane];
        #pragma unroll
        for (int i = 1; i < 16; i++) s += psum[i][lane];
        float dmax = wmax64(s);
        if (lane == 0) {
            float sbar = 0.25f * (snegR[0] + snegR[1] + snegR[2] + snegR[3]);
            float fxv  = 0.25f * (mred[0] + mred[1] + mred[2] + mred[3]);
            out[b] = (sbar + dmax) + fxv - kldG[b];
        }
    }
}

extern "C" void kernel_launch(void* const* d_in, const int* in_sizes, int n_in,
                              void* d_out, int out_size, void* d_ws, size_t ws_size,
                              hipStream_t stream) {
    const float* mean   = (const float*)d_in[0];
    const float* logvar = (const float*)d_in[1];
    const float* eps    = (const float*)d_in[2];
    const float* W1     = (const float*)d_in[3];
    const float* b1     = (const float*)d_in[4];
    const float* WA     = (const float*)d_in[5];
    const float* bA     = (const float*)d_in[6];
    const float* WF     = (const float*)d_in[7];
    const float* bF     = (const float*)d_in[8];
    const float* A      = (const float*)d_in[9];
    const float* Fx     = (const float*)d_in[10];
    const float* coeff  = (const float*)d_in[11];
    const int*   perms  = (const int*)d_in[12];
    float* out = (float*)d_out;

    ushort* Wt   = (ushort*)d_ws;               // 1408*1024 bf16
    ushort* hB   = Wt + NPAD * 1024;            // 1024*1024 bf16
    float*  Lbar = (float*)(hB + 1024 * 1024);  // 256*1225
    float*  SnegP = Lbar + BB * EE;             // 256*4*44 partials (written by k2)
    float*  lgF  = SnegP + 256 * 4 * 44;        // 1024*150
    int*    edgesG = (int*)(lgF + 1024 * 150);  // 256*256
    int*    cntG   = edgesG + 256 * 256;        // 256
    float*  kldG   = (float*)(cntG + 256);      // 256
    int*    ipG    = (int*)(kldG + 256);        // 64*51

    kA<<<dim3(868), dim3(256), 0, stream>>>(mean, logvar, eps, W1, b1, WA, WF, A, perms,
                                            hB, Wt, edgesG, cntG, kldG, ipG);
    k2<<<dim3(22, 32), dim3(256), 0, stream>>>(hB, Wt, bA, bF, Lbar, SnegP, lgF);
    k4<<<dim3(BB), dim3(1024), 0, stream>>>(Fx, coeff, ipG, Lbar, SnegP, lgF,
                                            edgesG, cntG, kldG, out);
}